// Round 10
// baseline (392.287 us; speedup 1.0000x reference)
//
#include <hip/hip_runtime.h>
#include <stdint.h>

typedef unsigned int u32;
typedef unsigned short u16;
typedef __bf16 bf16x8 __attribute__((ext_vector_type(8)));
typedef float floatx4 __attribute__((ext_vector_type(4)));
typedef u32 u32x4 __attribute__((ext_vector_type(4)));

__device__ __forceinline__ u16 f2b(float f) {
    u32 u = __builtin_bit_cast(u32, f);
    u32 r = u + 0x7FFFu + ((u >> 16) & 1u);
    return (u16)(r >> 16);
}
__device__ __forceinline__ float lo2f(u32 u) { return __builtin_bit_cast(float, u << 16); }
__device__ __forceinline__ float hi2f(u32 u) { return __builtin_bit_cast(float, u & 0xFFFF0000u); }

// ---------------- wave-uniform self-detection ----------------
__device__ __forceinline__ void self_detect(const int* ei, const u32* xw, int& is64, int& isbf) {
    int lane = threadIdx.x & 63;
    int v = ei ? ei[2 * lane + 1] : 0;
    unsigned long long b1 = __ballot(v == 0);
    u32 w = xw ? xw[lane] : 0;
    u32 e = (w >> 7) & 0xFF;
    int plaus = (e == 0) || (e >= 90 && e <= 140);
    unsigned long long b2 = __ballot(plaus);
    is64 = (b1 == ~0ULL) ? 1 : 0;
    isbf = (b2 == ~0ULL) ? 1 : 0;
}

__device__ __forceinline__ float load_f(const void* __restrict__ p, int isbf, size_t i) {
    if (isbf) {
        u16 s = ((const u16*)p)[i];
        return __builtin_bit_cast(float, ((u32)s) << 16);
    }
    return ((const float*)p)[i];
}

// ---------------- merged front: convert_x + wprep + smalls + bucket_scatter ----------------
// wprep packs Wcp for 16x16x32 MFMA B-frag (verified correct in R7/R9 runs):
//   chunk t in [0,4096): l=t&63, c=t>>6, sk=c>>3 (K-step), jt=c&7
//   Wcp[t*8+e] = B[k = sk*32 + (l>>4)*8 + e][j = jt*16 + (l&15)]
//   B[k][j] = (k<128) ? Wl[j][k] : Wr[j][k-128]
#define CH 4096
#define CAPB 3072

__global__ __launch_bounds__(1024) void front_kernel(
    const void* __restrict__ xraw, const int* __restrict__ ei, int E, int N, int cvb,
    u32* __restrict__ xb, int* __restrict__ gcur, u32* __restrict__ csrbkt,
    const void* Wl1, const void* Wr1, const void* Wl2, const void* Wr2,
    const void* Wl3, const void* Wr3, const void* b1, const void* b2,
    const void* b3, const void* Wo, const void* bo,
    u16* __restrict__ Wcp, float* __restrict__ smalls) {
    __shared__ int lhist[1024], loff[1024], lcur[1024], gofs[1024], wsum[16];
    __shared__ u32 ebuf[CH];
    __shared__ u16 ebkt[CH];
    int blk = blockIdx.x;
    int t = threadIdx.x;

    if (blk < cvb) {
        int is64, isbf;
        self_detect(nullptr, (const u32*)xraw, is64, isbf);
        int i = blk * 1024 + t;
        int count4 = N * 16;
        if (i >= count4) return;
        if (isbf) {
            ((u32x4*)xb)[i] = ((const u32x4*)xraw)[i];
        } else {
            typedef float fx4 __attribute__((ext_vector_type(4)));
            const fx4* f4 = (const fx4*)xraw;
            fx4 f0 = f4[2 * i], f1 = f4[2 * i + 1];
            u32x4 o;
            o.x = (u32)f2b(f0.x) | ((u32)f2b(f0.y) << 16);
            o.y = (u32)f2b(f0.z) | ((u32)f2b(f0.w) << 16);
            o.z = (u32)f2b(f1.x) | ((u32)f2b(f1.y) << 16);
            o.w = (u32)f2b(f1.z) | ((u32)f2b(f1.w) << 16);
            ((u32x4*)xb)[i] = o;
        }
        return;
    }
    if (blk < cvb + 12) {
        int is64, isbf;
        self_detect(nullptr, (const u32*)xraw, is64, isbf);
        int tg = (blk - cvb) * 1024 + t;  // 0..12287
        int l = tg >> 12;
        int tt = tg & 4095;
        const void* Wl = (l == 0) ? Wl1 : (l == 1) ? Wl2 : Wl3;
        const void* Wr = (l == 0) ? Wr1 : (l == 1) ? Wr2 : Wr3;
        u16* Wout = Wcp + (size_t)l * 32768;
        int ln = tt & 63;
        int c = tt >> 6;   // 0..63
        int sk = c >> 3;   // K-step 0..7
        int jt = c & 7;    // col-tile 0..7
        int j = jt * 16 + (ln & 15);
        int kb = sk * 32 + (ln >> 4) * 8;
#pragma unroll
        for (int jj = 0; jj < 8; ++jj) {
            int k = kb + jj;
            float v = (k < 128) ? load_f(Wl, isbf, (size_t)j * 128 + k)
                                : load_f(Wr, isbf, (size_t)j * 128 + (k - 128));
            Wout[tt * 8 + jj] = f2b(v);
        }
        return;
    }
    if (blk == cvb + 12) {
        int is64, isbf;
        self_detect(nullptr, (const u32*)xraw, is64, isbf);
        if (t < 642) {
            float v;
            if (t < 128) v = load_f(b1, isbf, t);
            else if (t < 256) v = load_f(b2, isbf, t - 128);
            else if (t < 384) v = load_f(b3, isbf, t - 256);
            else if (t < 640) v = load_f(Wo, isbf, t - 384);
            else v = load_f(bo, isbf, t - 640);
            smalls[t] = v;
        }
        return;
    }

    // ---- scatter role ----
    int is64, isbf;
    self_detect(ei, nullptr, is64, isbf);
    int cbase = (blk - (cvb + 13)) * CH;
    int cn = E - cbase;
    if (cn > CH) cn = CH;
    lhist[t] = 0;
    __syncthreads();
    int mysrc[4], myb[4], mydl[4];
#pragma unroll
    for (int k = 0; k < 4; ++k) {
        int i = t + k * 1024;
        myb[k] = -1;
        if (i < cn) {
            int e = cbase + i;
            int s, d;
            if (is64) {
                s = (int)((const uint2*)ei)[(size_t)e].x;
                d = (int)((const uint2*)ei)[(size_t)E + e].x;
            } else {
                s = ei[(size_t)e];
                d = ei[(size_t)E + e];
            }
            if ((unsigned)s >= (unsigned)N) s = 0;
            if ((unsigned)d >= (unsigned)N) d = 0;
            mysrc[k] = s;
            mydl[k] = d & 255;
            myb[k] = d >> 8;
            atomicAdd(&lhist[myb[k]], 1);
        }
    }
    __syncthreads();
    int lane = t & 63, wid = t >> 6;
    int v = lhist[t];
    int inc = v;
#pragma unroll
    for (int off = 1; off < 64; off <<= 1) {
        int o = __shfl_up(inc, off);
        if (lane >= off) inc += o;
    }
    if (lane == 63) wsum[wid] = inc;
    __syncthreads();
    int wpre = 0;
    for (int w = 0; w < wid; ++w) wpre += wsum[w];
    int excl = wpre + inc - v;
    loff[t] = excl;
    lcur[t] = excl;
    if (v > 0) gofs[t] = atomicAdd(&gcur[t], v);
    __syncthreads();
#pragma unroll
    for (int k = 0; k < 4; ++k) {
        if (myb[k] >= 0) {
            int pos = atomicAdd(&lcur[myb[k]], 1);
            ebuf[pos] = (u32)mysrc[k] | ((u32)mydl[k] << 24);
            ebkt[pos] = (u16)myb[k];
        }
    }
    __syncthreads();
#pragma unroll
    for (int k = 0; k < 4; ++k) {
        int i = t + k * 1024;
        if (i < cn) {
            int bb = ebkt[i];
            int local = gofs[bb] + (i - loff[bb]);
            if (local < CAPB) csrbkt[(size_t)bb * CAPB + local] = ebuf[i];
        }
    }
}

// one block per bucket: counting-sort by dst-low, compact into csr via gtot cursor
__global__ __launch_bounds__(512) void csr_build_kernel(
    const u32* __restrict__ csrbkt, const int* __restrict__ gcur,
    int N, int* __restrict__ gtot,
    int* __restrict__ offs, int* __restrict__ cnt,
    int* __restrict__ csr) {
    __shared__ int lh[256], lcur[256], wsum[4];
    __shared__ int sbase;
    __shared__ u32 sbuf[CAPB];
    int t = threadIdx.x;  // 512
    int b = blockIdx.x;
    int cb = gcur[b];
    if (cb > CAPB) cb = CAPB;
    const u32* bsrc = csrbkt + (size_t)b * CAPB;
    int d0 = b << 8;
    if (t < 256) lh[t] = 0;
    __syncthreads();
    for (int i = t; i < cb; i += 512) atomicAdd(&lh[bsrc[i] >> 24], 1);
    __syncthreads();
    int lane = t & 63, wid = t >> 6;
    if (t < 256) {
        int v = lh[t];
        int inc = v;
#pragma unroll
        for (int off = 1; off < 64; off <<= 1) {
            int o = __shfl_up(inc, off);
            if (lane >= off) inc += o;
        }
        if (lane == 63) wsum[wid] = inc;
    }
    __syncthreads();
    if (t < 256) {
        int v = lh[t];
        int inc = v;
#pragma unroll
        for (int off = 1; off < 64; off <<= 1) {
            int o = __shfl_up(inc, off);
            if (lane >= off) inc += o;
        }
        int wpre = 0;
        for (int w = 0; w < wid; ++w) wpre += wsum[w];
        int excl = wpre + inc - v;
        lcur[t] = excl;
        int d = d0 + t;
        if (d < N) {
            lh[t] = excl;  // stash excl (reuse lh)
            cnt[d] = v;
        }
    }
    if (t == 0) sbase = atomicAdd(gtot, cb);
    __syncthreads();
    int base = sbase;
    if (t < 256) {
        int d = d0 + t;
        if (d < N) offs[d] = base + lh[t];
    }
    for (int i = t; i < cb; i += 512) {
        u32 e = bsrc[i];
        int pos = atomicAdd(&lcur[e >> 24], 1);
        sbuf[pos] = e & 0xFFFFFFu;
    }
    __syncthreads();
    for (int i = t; i < cb; i += 512) csr[base + i] = (int)sbuf[i];
}

// ---------------- fused layer v3: B + own-A hoisted to registers ----------------
// Same proven-agg-grid fusion as R9 (70.4 µs measured), minus the 28 µs GEMM
// phase: R9's VGPR=36 shows B was re-loaded from L2 serially inside the MFMA
// loop (8 x ~250 cy critical path), and phase-lockstepped blocks exposed it.
// Now B (block-invariant, 16 KB/wave = 64 VGPR) and the own-feature A half
// (gather-independent, 16 VGPR) are loaded at kernel entry, before the
// gather; __syncthreads is a memory fence so they cannot sink past it.
// Post-barrier GEMM = 8 x {LDS A-read + 2 MFMA} ~ 600 cy: lockstep harmless.
// __launch_bounds__(256,4): pin VGPR <= 128 (16 waves/CU tier).
__global__ __launch_bounds__(256, 4) void layer_kernel(
    const u32* __restrict__ xcur, u32* __restrict__ xnxt,
    const int* __restrict__ offs, const int* __restrict__ cnt,
    const int* __restrict__ csr,
    const u16* __restrict__ Wcp, const float* __restrict__ biasf,
    int N, int relu, const float* __restrict__ headw,
    const u32* __restrict__ xw, void* __restrict__ outp, int tstride) {
    __shared__ u32 aggL[16][68];
    __shared__ float hsum[16][2];
    int sub = blockIdx.x / tstride;
    int tile = blockIdx.x % tstride;
    int t = threadIdx.x;
    int w = t >> 6;
    int lane = t & 63;
    int nd0b = tile * 128 + sub * 16;
    if (nd0b >= N) return;

    int r16 = lane & 15;
    int g4 = lane >> 4;
    int noder = nd0b + r16;
    int nodeC = (noder < N) ? noder : (N - 1);

    // ---- hoist phase: B-frags (block-invariant) + own-row A (gather-indep) ----
    const u16* bbase = Wcp + (size_t)lane * 8 + (size_t)(w * 2) * 512;
    bf16x8 B0[8], B1[8];
#pragma unroll
    for (int s = 0; s < 8; ++s) {
        const u16* bp = bbase + (size_t)(s * 8) * 512;
        B0[s] = *reinterpret_cast<const bf16x8*>(bp);
        B1[s] = *reinterpret_cast<const bf16x8*>(bp + 512);
    }
    bf16x8 aOwn[4];
#pragma unroll
    for (int s = 0; s < 4; ++s)
        aOwn[s] = *reinterpret_cast<const bf16x8*>(
            xcur + (size_t)nodeC * 64 + s * 16 + g4 * 4);

    if (t < 32) ((float*)hsum)[t] = 0.f;

    // ---- gather phase (byte-equivalent to proven agg; output -> LDS) ----
    int nd0 = nd0b + w * 4;
    int nd1 = nd0 + 4 < N ? nd0 + 4 : N;
    for (int nd = nd0; nd < nd1; ++nd) {
        int start = offs[nd];
        int num = cnt[nd];
        float a0 = 0.f, a1 = 0.f;
        int i = 0;
        for (; i + 8 <= num; i += 8) {
            int s0 = csr[start + i + 0], s1 = csr[start + i + 1];
            int s2 = csr[start + i + 2], s3 = csr[start + i + 3];
            int s4 = csr[start + i + 4], s5 = csr[start + i + 5];
            int s6 = csr[start + i + 6], s7 = csr[start + i + 7];
            u32 u0 = xcur[(size_t)s0 * 64 + lane];
            u32 u1 = xcur[(size_t)s1 * 64 + lane];
            u32 u2 = xcur[(size_t)s2 * 64 + lane];
            u32 u3 = xcur[(size_t)s3 * 64 + lane];
            u32 u4 = xcur[(size_t)s4 * 64 + lane];
            u32 u5 = xcur[(size_t)s5 * 64 + lane];
            u32 u6 = xcur[(size_t)s6 * 64 + lane];
            u32 u7 = xcur[(size_t)s7 * 64 + lane];
            a0 += lo2f(u0) + lo2f(u1) + lo2f(u2) + lo2f(u3) +
                  lo2f(u4) + lo2f(u5) + lo2f(u6) + lo2f(u7);
            a1 += hi2f(u0) + hi2f(u1) + hi2f(u2) + hi2f(u3) +
                  hi2f(u4) + hi2f(u5) + hi2f(u6) + hi2f(u7);
        }
        for (; i + 4 <= num; i += 4) {
            int s0 = csr[start + i + 0], s1 = csr[start + i + 1];
            int s2 = csr[start + i + 2], s3 = csr[start + i + 3];
            u32 u0 = xcur[(size_t)s0 * 64 + lane];
            u32 u1 = xcur[(size_t)s1 * 64 + lane];
            u32 u2 = xcur[(size_t)s2 * 64 + lane];
            u32 u3 = xcur[(size_t)s3 * 64 + lane];
            a0 += lo2f(u0) + lo2f(u1) + lo2f(u2) + lo2f(u3);
            a1 += hi2f(u0) + hi2f(u1) + hi2f(u2) + hi2f(u3);
        }
        for (; i < num; ++i) {
            u32 u = xcur[(size_t)csr[start + i] * 64 + lane];
            a0 += lo2f(u);
            a1 += hi2f(u);
        }
        float sc = 1.0f / (float)(num > 1 ? num : 1);
        a0 *= sc;
        a1 *= sc;
        aggL[nd - nd0b][lane] = (u32)f2b(a0) | ((u32)f2b(a1) << 16);
    }
    __syncthreads();

    // ---- MFMA phase: register-resident, ~600 cycles ----
    floatx4 acc0 = 0.0f, acc1 = 0.0f;
#pragma unroll
    for (int s = 0; s < 8; ++s) {
        bf16x8 a = (s < 4)
            ? *reinterpret_cast<const bf16x8*>(&aggL[r16][s * 16 + g4 * 4])
            : aOwn[s - 4];
        acc0 = __builtin_amdgcn_mfma_f32_16x16x32_bf16(a, B0[s], acc0, 0, 0, 0);
        acc1 = __builtin_amdgcn_mfma_f32_16x16x32_bf16(a, B1[s], acc1, 0, 0, 0);
    }
    __syncthreads();  // A-reads done (aggL reusable); hsum-zero visible

    // C/D: col = lane&15 (+tile base), row = (lane>>4)*4 + r  [verified m89/m91]
    if (outp == nullptr) {
        u16* ldsO = (u16*)aggL;  // [16][136] u16 view
        int col0 = w * 32 + r16;
        float bf0 = biasf[col0], bf1 = biasf[col0 + 16];
#pragma unroll
        for (int r = 0; r < 4; ++r) {
            int row = g4 * 4 + r;
            float v0 = acc0[r] + bf0;
            float v1 = acc1[r] + bf1;
            if (relu) { v0 = fmaxf(v0, 0.0f); v1 = fmaxf(v1, 0.0f); }
            ldsO[row * 136 + col0] = f2b(v0);
            ldsO[row * 136 + col0 + 16] = f2b(v1);
        }
        __syncthreads();
        int row = t >> 4, seg = t & 15;
        int nodeS = nd0b + row;
        if (nodeS < N) {
            const u16* lp = ldsO + row * 136 + seg * 8;
            uint2 lo = *reinterpret_cast<const uint2*>(lp);
            uint2 hi = *reinterpret_cast<const uint2*>(lp + 4);
            u32x4 o;
            o.x = lo.x; o.y = lo.y; o.z = hi.x; o.w = hi.y;
            *reinterpret_cast<u32x4*>(&xnxt[(size_t)nodeS * 64 + seg * 4]) = o;
        }
    } else {
        // fused head: h = acc + bl3; out = (h.Wo0 + bo0, h.Wo1 + bo1)
        int is64, isbf;
        self_detect(nullptr, xw, is64, isbf);  // full wave active
        int col0 = w * 32 + r16;
        int col1 = col0 + 16;
        float bf0 = biasf[col0], bf1 = biasf[col1];
        float w00 = headw[col0], w01 = headw[col1];
        float w10 = headw[128 + col0], w11 = headw[128 + col1];
#pragma unroll
        for (int r = 0; r < 4; ++r) {
            float h0 = acc0[r] + bf0;
            float h1 = acc1[r] + bf1;
            float p0 = h0 * w00 + h1 * w01;
            float p1 = h0 * w10 + h1 * w11;
#pragma unroll
            for (int off = 8; off > 0; off >>= 1) {
                p0 += __shfl_xor(p0, off);
                p1 += __shfl_xor(p1, off);
            }
            if (r16 == 0) {
                atomicAdd(&hsum[g4 * 4 + r][0], p0);
                atomicAdd(&hsum[g4 * 4 + r][1], p1);
            }
        }
        __syncthreads();
        if (t < 16) {
            int nodeS = nd0b + t;
            if (nodeS < N) {
                float o0 = hsum[t][0] + headw[256];  // bo0
                float o1 = hsum[t][1] + headw[257];  // bo1
                if (isbf)
                    ((u32*)outp)[nodeS] = (u32)f2b(o0) | ((u32)f2b(o1) << 16);
                else
                    ((float2*)outp)[nodeS] = make_float2(o0, o1);
            }
        }
    }
}

extern "C" void kernel_launch(void* const* d_in, const int* in_sizes, int n_in,
                              void* d_out, int out_size, void* d_ws, size_t ws_size,
                              hipStream_t stream) {
    const int N = in_sizes[0] / 128;
    const int E = in_sizes[1] / 2;

    const void* x = d_in[0];
    const int* ei = (const int*)d_in[1];
    const void* Wl[3] = {d_in[2], d_in[5], d_in[8]};
    const void* bl[3] = {d_in[3], d_in[6], d_in[9]};
    const void* Wr[3] = {d_in[4], d_in[7], d_in[10]};
    const void* Wo = d_in[11];
    const void* bo = d_in[12];

    // workspace bump allocator (256B aligned)
    char* p = (char*)d_ws;
    auto alloc = [&](size_t bytes) -> char* {
        char* r = p;
        p += (bytes + 255) & ~(size_t)255;
        return r;
    };
    int* offs = (int*)alloc((size_t)N * 4);
    int* cnt = (int*)alloc((size_t)N * 4);
    float* smalls = (float*)alloc(642 * 4);
    int* gcur = (int*)alloc(1025 * 4);  // [1024] = gtot
    int* csr = (int*)alloc(((size_t)E + CAPB + 64) * 4);  // over-alloc: padded reads safe
    u16* Wcp = (u16*)alloc((size_t)3 * 4096 * 8 * 2);
    u32* x0 = (u32*)alloc((size_t)(N + 1) * 64 * 4);
    u32* x1 = (u32*)alloc((size_t)(N + 1) * 64 * 4);  // aliased as csrbkt during build
    u32* csrbkt = x1;                                  // dead until layers start
    int* gtot = gcur + 1024;
    (void)ws_size;

    const int NB = (N + 255) / 256;          // buckets
    const int cvb = (N * 16 + 1023) / 1024;  // convert blocks (1024 thr)
    const int sb = (E + CH - 1) / CH;        // scatter blocks
    const int gb = (N + 127) / 128;          // tiles (128 nodes)
    const int tstride = (gb + 7) & ~7;       // tile stride, mult of 8 (XCD affinity)
    const int ab = 8 * tstride;              // layer blocks: 8 sub-blocks x tstride tiles

    hipMemsetAsync(gcur, 0, 1025 * 4, stream);
    front_kernel<<<cvb + 13 + sb, 1024, 0, stream>>>(
        x, ei, E, N, cvb, x0, gcur, csrbkt,
        Wl[0], Wr[0], Wl[1], Wr[1], Wl[2], Wr[2],
        bl[0], bl[1], bl[2], Wo, bo, Wcp, smalls);
    csr_build_kernel<<<NB, 512, 0, stream>>>(csrbkt, gcur, N, gtot, offs, cnt, csr);

    // layer 1: x0 -> x1
    layer_kernel<<<ab, 256, 0, stream>>>(x0, x1, offs, cnt, csr, Wcp, smalls, N, 1,
                                         nullptr, nullptr, nullptr, tstride);
    // layer 2: x1 -> x0
    layer_kernel<<<ab, 256, 0, stream>>>(x1, x0, offs, cnt, csr, Wcp + 32768, smalls + 128, N, 1,
                                         nullptr, nullptr, nullptr, tstride);
    // layer 3 + fused head: x0 -> d_out
    layer_kernel<<<ab, 256, 0, stream>>>(x0, x1, offs, cnt, csr, Wcp + 65536, smalls + 256, N, 0,
                                         smalls + 384, (const u32*)x, d_out, tstride);
}

// Round 11
// 383.987 us; speedup vs baseline: 1.0216x; 1.0216x over previous
//
#include <hip/hip_runtime.h>
#include <stdint.h>

typedef unsigned int u32;
typedef unsigned short u16;
typedef __bf16 bf16x8 __attribute__((ext_vector_type(8)));
typedef float floatx4 __attribute__((ext_vector_type(4)));
typedef u32 u32x4 __attribute__((ext_vector_type(4)));

__device__ __forceinline__ u16 f2b(float f) {
    u32 u = __builtin_bit_cast(u32, f);
    u32 r = u + 0x7FFFu + ((u >> 16) & 1u);
    return (u16)(r >> 16);
}
__device__ __forceinline__ float lo2f(u32 u) { return __builtin_bit_cast(float, u << 16); }
__device__ __forceinline__ float hi2f(u32 u) { return __builtin_bit_cast(float, u & 0xFFFF0000u); }

// ---------------- wave-uniform self-detection ----------------
__device__ __forceinline__ void self_detect(const int* ei, const u32* xw, int& is64, int& isbf) {
    int lane = threadIdx.x & 63;
    int v = ei ? ei[2 * lane + 1] : 0;
    unsigned long long b1 = __ballot(v == 0);
    u32 w = xw ? xw[lane] : 0;
    u32 e = (w >> 7) & 0xFF;
    int plaus = (e == 0) || (e >= 90 && e <= 140);
    unsigned long long b2 = __ballot(plaus);
    is64 = (b1 == ~0ULL) ? 1 : 0;
    isbf = (b2 == ~0ULL) ? 1 : 0;
}

__device__ __forceinline__ float load_f(const void* __restrict__ p, int isbf, size_t i) {
    if (isbf) {
        u16 s = ((const u16*)p)[i];
        return __builtin_bit_cast(float, ((u32)s) << 16);
    }
    return ((const float*)p)[i];
}

// ---------------- merged front: convert_x + wprep + smalls + bucket_scatter ----------------
// wprep packs Wcp for 16x16x32 MFMA B-frag (verified correct in R7/R9 runs):
//   chunk t in [0,4096): l=t&63, c=t>>6, sk=c>>3 (K-step), jt=c&7
//   Wcp[t*8+e] = B[k = sk*32 + (l>>4)*8 + e][j = jt*16 + (l&15)]
//   B[k][j] = (k<128) ? Wl[j][k] : Wr[j][k-128]
#define CH 4096
#define CAPB 3072

__global__ __launch_bounds__(1024) void front_kernel(
    const void* __restrict__ xraw, const int* __restrict__ ei, int E, int N, int cvb,
    u32* __restrict__ xb, int* __restrict__ gcur, u32* __restrict__ csrbkt,
    const void* Wl1, const void* Wr1, const void* Wl2, const void* Wr2,
    const void* Wl3, const void* Wr3, const void* b1, const void* b2,
    const void* b3, const void* Wo, const void* bo,
    u16* __restrict__ Wcp, float* __restrict__ smalls) {
    __shared__ int lhist[1024], loff[1024], lcur[1024], gofs[1024], wsum[16];
    __shared__ u32 ebuf[CH];
    __shared__ u16 ebkt[CH];
    int blk = blockIdx.x;
    int t = threadIdx.x;

    if (blk < cvb) {
        int is64, isbf;
        self_detect(nullptr, (const u32*)xraw, is64, isbf);
        int i = blk * 1024 + t;
        int count4 = N * 16;
        if (i >= count4) return;
        if (isbf) {
            ((u32x4*)xb)[i] = ((const u32x4*)xraw)[i];
        } else {
            typedef float fx4 __attribute__((ext_vector_type(4)));
            const fx4* f4 = (const fx4*)xraw;
            fx4 f0 = f4[2 * i], f1 = f4[2 * i + 1];
            u32x4 o;
            o.x = (u32)f2b(f0.x) | ((u32)f2b(f0.y) << 16);
            o.y = (u32)f2b(f0.z) | ((u32)f2b(f0.w) << 16);
            o.z = (u32)f2b(f1.x) | ((u32)f2b(f1.y) << 16);
            o.w = (u32)f2b(f1.z) | ((u32)f2b(f1.w) << 16);
            ((u32x4*)xb)[i] = o;
        }
        return;
    }
    if (blk < cvb + 12) {
        int is64, isbf;
        self_detect(nullptr, (const u32*)xraw, is64, isbf);
        int tg = (blk - cvb) * 1024 + t;  // 0..12287
        int l = tg >> 12;
        int tt = tg & 4095;
        const void* Wl = (l == 0) ? Wl1 : (l == 1) ? Wl2 : Wl3;
        const void* Wr = (l == 0) ? Wr1 : (l == 1) ? Wr2 : Wr3;
        u16* Wout = Wcp + (size_t)l * 32768;
        int ln = tt & 63;
        int c = tt >> 6;   // 0..63
        int sk = c >> 3;   // K-step 0..7
        int jt = c & 7;    // col-tile 0..7
        int j = jt * 16 + (ln & 15);
        int kb = sk * 32 + (ln >> 4) * 8;
#pragma unroll
        for (int jj = 0; jj < 8; ++jj) {
            int k = kb + jj;
            float v = (k < 128) ? load_f(Wl, isbf, (size_t)j * 128 + k)
                                : load_f(Wr, isbf, (size_t)j * 128 + (k - 128));
            Wout[tt * 8 + jj] = f2b(v);
        }
        return;
    }
    if (blk == cvb + 12) {
        int is64, isbf;
        self_detect(nullptr, (const u32*)xraw, is64, isbf);
        if (t < 642) {
            float v;
            if (t < 128) v = load_f(b1, isbf, t);
            else if (t < 256) v = load_f(b2, isbf, t - 128);
            else if (t < 384) v = load_f(b3, isbf, t - 256);
            else if (t < 640) v = load_f(Wo, isbf, t - 384);
            else v = load_f(bo, isbf, t - 640);
            smalls[t] = v;
        }
        return;
    }

    // ---- scatter role ----
    int is64, isbf;
    self_detect(ei, nullptr, is64, isbf);
    int cbase = (blk - (cvb + 13)) * CH;
    int cn = E - cbase;
    if (cn > CH) cn = CH;
    lhist[t] = 0;
    __syncthreads();
    int mysrc[4], myb[4], mydl[4];
#pragma unroll
    for (int k = 0; k < 4; ++k) {
        int i = t + k * 1024;
        myb[k] = -1;
        if (i < cn) {
            int e = cbase + i;
            int s, d;
            if (is64) {
                s = (int)((const uint2*)ei)[(size_t)e].x;
                d = (int)((const uint2*)ei)[(size_t)E + e].x;
            } else {
                s = ei[(size_t)e];
                d = ei[(size_t)E + e];
            }
            if ((unsigned)s >= (unsigned)N) s = 0;
            if ((unsigned)d >= (unsigned)N) d = 0;
            mysrc[k] = s;
            mydl[k] = d & 255;
            myb[k] = d >> 8;
            atomicAdd(&lhist[myb[k]], 1);
        }
    }
    __syncthreads();
    int lane = t & 63, wid = t >> 6;
    int v = lhist[t];
    int inc = v;
#pragma unroll
    for (int off = 1; off < 64; off <<= 1) {
        int o = __shfl_up(inc, off);
        if (lane >= off) inc += o;
    }
    if (lane == 63) wsum[wid] = inc;
    __syncthreads();
    int wpre = 0;
    for (int w = 0; w < wid; ++w) wpre += wsum[w];
    int excl = wpre + inc - v;
    loff[t] = excl;
    lcur[t] = excl;
    if (v > 0) gofs[t] = atomicAdd(&gcur[t], v);
    __syncthreads();
#pragma unroll
    for (int k = 0; k < 4; ++k) {
        if (myb[k] >= 0) {
            int pos = atomicAdd(&lcur[myb[k]], 1);
            ebuf[pos] = (u32)mysrc[k] | ((u32)mydl[k] << 24);
            ebkt[pos] = (u16)myb[k];
        }
    }
    __syncthreads();
#pragma unroll
    for (int k = 0; k < 4; ++k) {
        int i = t + k * 1024;
        if (i < cn) {
            int bb = ebkt[i];
            int local = gofs[bb] + (i - loff[bb]);
            if (local < CAPB) csrbkt[(size_t)bb * CAPB + local] = ebuf[i];
        }
    }
}

// one block per bucket: counting-sort by dst-low, compact into csr via gtot cursor
__global__ __launch_bounds__(512) void csr_build_kernel(
    const u32* __restrict__ csrbkt, const int* __restrict__ gcur,
    int N, int* __restrict__ gtot,
    int* __restrict__ offs, int* __restrict__ cnt,
    int* __restrict__ csr) {
    __shared__ int lh[256], lcur[256], wsum[4];
    __shared__ int sbase;
    __shared__ u32 sbuf[CAPB];
    int t = threadIdx.x;  // 512
    int b = blockIdx.x;
    int cb = gcur[b];
    if (cb > CAPB) cb = CAPB;
    const u32* bsrc = csrbkt + (size_t)b * CAPB;
    int d0 = b << 8;
    if (t < 256) lh[t] = 0;
    __syncthreads();
    for (int i = t; i < cb; i += 512) atomicAdd(&lh[bsrc[i] >> 24], 1);
    __syncthreads();
    int lane = t & 63, wid = t >> 6;
    if (t < 256) {
        int v = lh[t];
        int inc = v;
#pragma unroll
        for (int off = 1; off < 64; off <<= 1) {
            int o = __shfl_up(inc, off);
            if (lane >= off) inc += o;
        }
        if (lane == 63) wsum[wid] = inc;
    }
    __syncthreads();
    if (t < 256) {
        int v = lh[t];
        int inc = v;
#pragma unroll
        for (int off = 1; off < 64; off <<= 1) {
            int o = __shfl_up(inc, off);
            if (lane >= off) inc += o;
        }
        int wpre = 0;
        for (int w = 0; w < wid; ++w) wpre += wsum[w];
        int excl = wpre + inc - v;
        lcur[t] = excl;
        int d = d0 + t;
        if (d < N) {
            lh[t] = excl;  // stash excl (reuse lh)
            cnt[d] = v;
        }
    }
    if (t == 0) sbase = atomicAdd(gtot, cb);
    __syncthreads();
    int base = sbase;
    if (t < 256) {
        int d = d0 + t;
        if (d < N) offs[d] = base + lh[t];
    }
    for (int i = t; i < cb; i += 512) {
        u32 e = bsrc[i];
        int pos = atomicAdd(&lcur[e >> 24], 1);
        sbuf[pos] = e & 0xFFFFFFu;
    }
    __syncthreads();
    for (int i = t; i < cb; i += 512) csr[base + i] = (int)sbuf[i];
}

// ---------------- fused layer v4: wave-independent, ZERO barriers ----------------
// R9's 28 µs GEMM-phase exposure was barrier lockstep (max-of-4 gather tails +
// co-resident blocks hitting the serial B-load/MFMA phase together). R10's
// cross-phase register hoist failed (compiler spilled, VGPR=60, occ 38%).
// v4: each WAVE owns 16 nodes end-to-end. Gather its 16 rows into its own LDS
// quadrant (proven 8-deep-unroll inner loop, byte-identical), then immediately
// run its own 16x128 GEMM (A = own LDS rows + own xcur rows; B from L2-hot
// Wcp at GEMM time -- naturally staggered across waves), then per-wave LDS
// transpose epilogue / in-register head. No __syncthreads anywhere; in-wave
// DS ordering is guaranteed by compiler-inserted lgkmcnt waits.
// Block = 4 independent waves = 64 nodes; grid = ceil(N/64) = 1563 blocks.
__global__ __launch_bounds__(256, 4) void layer_kernel(
    const u32* __restrict__ xcur, u32* __restrict__ xnxt,
    const int* __restrict__ offs, const int* __restrict__ cnt,
    const int* __restrict__ csr,
    const u16* __restrict__ Wcp, const float* __restrict__ biasf,
    int N, int relu, const float* __restrict__ headw,
    const u32* __restrict__ xw, void* __restrict__ outp) {
    __shared__ u32 aggL[4][16][68];
    int t = threadIdx.x;
    int w = t >> 6;
    int lane = t & 63;
    int nd0w = blockIdx.x * 64 + w * 16;  // this wave's 16 nodes
    if (nd0w >= N) return;                 // wave-uniform
    int ndEnd = nd0w + 16 < N ? nd0w + 16 : N;

    // ---- gather phase (proven inner loop; wave-private LDS output) ----
    for (int nd = nd0w; nd < ndEnd; ++nd) {
        int start = offs[nd];
        int num = cnt[nd];
        float a0 = 0.f, a1 = 0.f;
        int i = 0;
        for (; i + 8 <= num; i += 8) {
            int s0 = csr[start + i + 0], s1 = csr[start + i + 1];
            int s2 = csr[start + i + 2], s3 = csr[start + i + 3];
            int s4 = csr[start + i + 4], s5 = csr[start + i + 5];
            int s6 = csr[start + i + 6], s7 = csr[start + i + 7];
            u32 u0 = xcur[(size_t)s0 * 64 + lane];
            u32 u1 = xcur[(size_t)s1 * 64 + lane];
            u32 u2 = xcur[(size_t)s2 * 64 + lane];
            u32 u3 = xcur[(size_t)s3 * 64 + lane];
            u32 u4 = xcur[(size_t)s4 * 64 + lane];
            u32 u5 = xcur[(size_t)s5 * 64 + lane];
            u32 u6 = xcur[(size_t)s6 * 64 + lane];
            u32 u7 = xcur[(size_t)s7 * 64 + lane];
            a0 += lo2f(u0) + lo2f(u1) + lo2f(u2) + lo2f(u3) +
                  lo2f(u4) + lo2f(u5) + lo2f(u6) + lo2f(u7);
            a1 += hi2f(u0) + hi2f(u1) + hi2f(u2) + hi2f(u3) +
                  hi2f(u4) + hi2f(u5) + hi2f(u6) + hi2f(u7);
        }
        for (; i + 4 <= num; i += 4) {
            int s0 = csr[start + i + 0], s1 = csr[start + i + 1];
            int s2 = csr[start + i + 2], s3 = csr[start + i + 3];
            u32 u0 = xcur[(size_t)s0 * 64 + lane];
            u32 u1 = xcur[(size_t)s1 * 64 + lane];
            u32 u2 = xcur[(size_t)s2 * 64 + lane];
            u32 u3 = xcur[(size_t)s3 * 64 + lane];
            a0 += lo2f(u0) + lo2f(u1) + lo2f(u2) + lo2f(u3);
            a1 += hi2f(u0) + hi2f(u1) + hi2f(u2) + hi2f(u3);
        }
        for (; i < num; ++i) {
            u32 u = xcur[(size_t)csr[start + i] * 64 + lane];
            a0 += lo2f(u);
            a1 += hi2f(u);
        }
        float sc = 1.0f / (float)(num > 1 ? num : 1);
        a0 *= sc;
        a1 *= sc;
        aggL[w][nd - nd0w][lane] = (u32)f2b(a0) | ((u32)f2b(a1) << 16);
    }
    // no barrier: this wave reads only its own aggL quadrant (in-wave lgkm order)

    // ---- GEMM phase: this wave's 16 rows x 128 cols, K=256 ----
    int r16 = lane & 15;
    int g4 = lane >> 4;
    int noder = nd0w + r16;
    int nodeC = (noder < N) ? noder : (N - 1);
    floatx4 acc[8];
#pragma unroll
    for (int jt = 0; jt < 8; ++jt) acc[jt] = 0.0f;
    const u16* bl8 = Wcp + (size_t)lane * 8;
#pragma unroll
    for (int s = 0; s < 8; ++s) {
        bf16x8 a = (s < 4)
            ? *reinterpret_cast<const bf16x8*>(&aggL[w][r16][s * 16 + g4 * 4])
            : *reinterpret_cast<const bf16x8*>(
                  xcur + (size_t)nodeC * 64 + (s - 4) * 16 + g4 * 4);
#pragma unroll
        for (int jt = 0; jt < 8; ++jt) {
            bf16x8 b = *reinterpret_cast<const bf16x8*>(bl8 + (size_t)(s * 8 + jt) * 512);
            acc[jt] = __builtin_amdgcn_mfma_f32_16x16x32_bf16(a, b, acc[jt], 0, 0, 0);
        }
    }

    // C/D: col = lane&15 (+jt*16), row = (lane>>4)*4 + r  [verified m89/m91]
    if (outp == nullptr) {
        // per-wave LDS transpose epilogue (reuse own aggL quadrant)
        u16* ldsO = (u16*)&aggL[w][0][0];  // [16][136] u16 view
#pragma unroll
        for (int jt = 0; jt < 8; ++jt) {
            int col = jt * 16 + r16;
            float bf = biasf[col];
#pragma unroll
            for (int r = 0; r < 4; ++r) {
                int row = g4 * 4 + r;
                float v = acc[jt][r] + bf;
                if (relu) v = fmaxf(v, 0.0f);
                ldsO[row * 136 + col] = f2b(v);
            }
        }
        // read back (in-wave order): lane -> row = lane>>2, seg = lane&3
        int row = lane >> 2;
        int seg = lane & 3;
        int nodeS = nd0w + row;
        if (nodeS < N) {
            u32* drow = &xnxt[(size_t)nodeS * 64 + seg * 16];
            const u16* lp = ldsO + row * 136 + seg * 32;
#pragma unroll
            for (int i = 0; i < 4; ++i) {
                uint2 lo = *reinterpret_cast<const uint2*>(lp + i * 8);
                uint2 hi = *reinterpret_cast<const uint2*>(lp + i * 8 + 4);
                u32x4 o;
                o.x = lo.x; o.y = lo.y; o.z = hi.x; o.w = hi.y;
                *reinterpret_cast<u32x4*>(drow + i * 4) = o;
            }
        }
    } else {
        // fused head, all-register: h = acc + bl3; out = (h.Wo0+bo0, h.Wo1+bo1)
        int is64, isbf;
        self_detect(nullptr, xw, is64, isbf);  // full wave active
        float p0 = 0.f, p1 = 0.f;
        float p0r[4], p1r[4];
#pragma unroll
        for (int r = 0; r < 4; ++r) { p0r[r] = 0.f; p1r[r] = 0.f; }
#pragma unroll
        for (int jt = 0; jt < 8; ++jt) {
            int col = jt * 16 + r16;
            float bf = biasf[col];
            float w0 = headw[col];
            float w1 = headw[128 + col];
#pragma unroll
            for (int r = 0; r < 4; ++r) {
                float h = acc[jt][r] + bf;
                p0r[r] += h * w0;
                p1r[r] += h * w1;
            }
        }
#pragma unroll
        for (int r = 0; r < 4; ++r) {
            p0 = p0r[r];
            p1 = p1r[r];
#pragma unroll
            for (int off = 8; off > 0; off >>= 1) {
                p0 += __shfl_xor(p0, off);
                p1 += __shfl_xor(p1, off);
            }
            if (r16 == 0) {
                int nodeS = nd0w + g4 * 4 + r;
                if (nodeS < N) {
                    float o0 = p0 + headw[256];  // bo0
                    float o1 = p1 + headw[257];  // bo1
                    if (isbf)
                        ((u32*)outp)[nodeS] = (u32)f2b(o0) | ((u32)f2b(o1) << 16);
                    else
                        ((float2*)outp)[nodeS] = make_float2(o0, o1);
                }
            }
        }
    }
}

extern "C" void kernel_launch(void* const* d_in, const int* in_sizes, int n_in,
                              void* d_out, int out_size, void* d_ws, size_t ws_size,
                              hipStream_t stream) {
    const int N = in_sizes[0] / 128;
    const int E = in_sizes[1] / 2;

    const void* x = d_in[0];
    const int* ei = (const int*)d_in[1];
    const void* Wl[3] = {d_in[2], d_in[5], d_in[8]};
    const void* bl[3] = {d_in[3], d_in[6], d_in[9]};
    const void* Wr[3] = {d_in[4], d_in[7], d_in[10]};
    const void* Wo = d_in[11];
    const void* bo = d_in[12];

    // workspace bump allocator (256B aligned)
    char* p = (char*)d_ws;
    auto alloc = [&](size_t bytes) -> char* {
        char* r = p;
        p += (bytes + 255) & ~(size_t)255;
        return r;
    };
    int* offs = (int*)alloc((size_t)N * 4);
    int* cnt = (int*)alloc((size_t)N * 4);
    float* smalls = (float*)alloc(642 * 4);
    int* gcur = (int*)alloc(1025 * 4);  // [1024] = gtot
    int* csr = (int*)alloc(((size_t)E + CAPB + 64) * 4);  // over-alloc: padded reads safe
    u16* Wcp = (u16*)alloc((size_t)3 * 4096 * 8 * 2);
    u32* x0 = (u32*)alloc((size_t)(N + 1) * 64 * 4);
    u32* x1 = (u32*)alloc((size_t)(N + 1) * 64 * 4);  // aliased as csrbkt during build
    u32* csrbkt = x1;                                  // dead until layers start
    int* gtot = gcur + 1024;
    (void)ws_size;

    const int NB = (N + 255) / 256;          // buckets
    const int cvb = (N * 16 + 1023) / 1024;  // convert blocks (1024 thr)
    const int sb = (E + CH - 1) / CH;        // scatter blocks
    const int lb = (N + 63) / 64;            // layer blocks (64 nodes each)

    hipMemsetAsync(gcur, 0, 1025 * 4, stream);
    front_kernel<<<cvb + 13 + sb, 1024, 0, stream>>>(
        x, ei, E, N, cvb, x0, gcur, csrbkt,
        Wl[0], Wr[0], Wl[1], Wr[1], Wl[2], Wr[2],
        bl[0], bl[1], bl[2], Wo, bo, Wcp, smalls);
    csr_build_kernel<<<NB, 512, 0, stream>>>(csrbkt, gcur, N, gtot, offs, cnt, csr);

    // layer 1: x0 -> x1
    layer_kernel<<<lb, 256, 0, stream>>>(x0, x1, offs, cnt, csr, Wcp, smalls, N, 1,
                                         nullptr, nullptr, nullptr);
    // layer 2: x1 -> x0
    layer_kernel<<<lb, 256, 0, stream>>>(x1, x0, offs, cnt, csr, Wcp + 32768, smalls + 128, N, 1,
                                         nullptr, nullptr, nullptr);
    // layer 3 + fused head: x0 -> d_out
    layer_kernel<<<lb, 256, 0, stream>>>(x0, x1, offs, cnt, csr, Wcp + 65536, smalls + 256, N, 0,
                                         smalls + 384, (const u32*)x, d_out);
}

// Round 12
// 310.314 us; speedup vs baseline: 1.2642x; 1.2374x over previous
//
#include <hip/hip_runtime.h>
#include <stdint.h>

typedef unsigned int u32;
typedef unsigned short u16;
typedef __bf16 bf16x8 __attribute__((ext_vector_type(8)));
typedef float floatx4 __attribute__((ext_vector_type(4)));
typedef u32 u32x4 __attribute__((ext_vector_type(4)));

__device__ __forceinline__ u16 f2b(float f) {
    u32 u = __builtin_bit_cast(u32, f);
    u32 r = u + 0x7FFFu + ((u >> 16) & 1u);
    return (u16)(r >> 16);
}
__device__ __forceinline__ float lo2f(u32 u) { return __builtin_bit_cast(float, u << 16); }
__device__ __forceinline__ float hi2f(u32 u) { return __builtin_bit_cast(float, u & 0xFFFF0000u); }

// ---------------- wave-uniform self-detection ----------------
__device__ __forceinline__ void self_detect(const int* ei, const u32* xw, int& is64, int& isbf) {
    int lane = threadIdx.x & 63;
    int v = ei ? ei[2 * lane + 1] : 0;
    unsigned long long b1 = __ballot(v == 0);
    u32 w = xw ? xw[lane] : 0;
    u32 e = (w >> 7) & 0xFF;
    int plaus = (e == 0) || (e >= 90 && e <= 140);
    unsigned long long b2 = __ballot(plaus);
    is64 = (b1 == ~0ULL) ? 1 : 0;
    isbf = (b2 == ~0ULL) ? 1 : 0;
}

__device__ __forceinline__ float load_f(const void* __restrict__ p, int isbf, size_t i) {
    if (isbf) {
        u16 s = ((const u16*)p)[i];
        return __builtin_bit_cast(float, ((u32)s) << 16);
    }
    return ((const float*)p)[i];
}

// ---------------- merged front: convert_x + wprep + smalls + bucket_scatter ----------------
// wprep packs Wcp for 16x16x32 MFMA B-frag (verified correct in R7/R9 runs):
//   chunk t in [0,4096): l=t&63, c=t>>6, sk=c>>3 (K-step), jt=c&7
//   Wcp[t*8+e] = B[k = sk*32 + (l>>4)*8 + e][j = jt*16 + (l&15)]
//   B[k][j] = (k<128) ? Wl[j][k] : Wr[j][k-128]
#define CH 4096
#define CAPB 3072

__global__ __launch_bounds__(1024) void front_kernel(
    const void* __restrict__ xraw, const int* __restrict__ ei, int E, int N, int cvb,
    u32* __restrict__ xb, int* __restrict__ gcur, u32* __restrict__ csrbkt,
    const void* Wl1, const void* Wr1, const void* Wl2, const void* Wr2,
    const void* Wl3, const void* Wr3, const void* b1, const void* b2,
    const void* b3, const void* Wo, const void* bo,
    u16* __restrict__ Wcp, float* __restrict__ smalls) {
    __shared__ int lhist[1024], loff[1024], lcur[1024], gofs[1024], wsum[16];
    __shared__ u32 ebuf[CH];
    __shared__ u16 ebkt[CH];
    int blk = blockIdx.x;
    int t = threadIdx.x;

    if (blk < cvb) {
        int is64, isbf;
        self_detect(nullptr, (const u32*)xraw, is64, isbf);
        int i = blk * 1024 + t;
        int count4 = N * 16;
        if (i >= count4) return;
        if (isbf) {
            ((u32x4*)xb)[i] = ((const u32x4*)xraw)[i];
        } else {
            typedef float fx4 __attribute__((ext_vector_type(4)));
            const fx4* f4 = (const fx4*)xraw;
            fx4 f0 = f4[2 * i], f1 = f4[2 * i + 1];
            u32x4 o;
            o.x = (u32)f2b(f0.x) | ((u32)f2b(f0.y) << 16);
            o.y = (u32)f2b(f0.z) | ((u32)f2b(f0.w) << 16);
            o.z = (u32)f2b(f1.x) | ((u32)f2b(f1.y) << 16);
            o.w = (u32)f2b(f1.z) | ((u32)f2b(f1.w) << 16);
            ((u32x4*)xb)[i] = o;
        }
        return;
    }
    if (blk < cvb + 12) {
        int is64, isbf;
        self_detect(nullptr, (const u32*)xraw, is64, isbf);
        int tg = (blk - cvb) * 1024 + t;  // 0..12287
        int l = tg >> 12;
        int tt = tg & 4095;
        const void* Wl = (l == 0) ? Wl1 : (l == 1) ? Wl2 : Wl3;
        const void* Wr = (l == 0) ? Wr1 : (l == 1) ? Wr2 : Wr3;
        u16* Wout = Wcp + (size_t)l * 32768;
        int ln = tt & 63;
        int c = tt >> 6;   // 0..63
        int sk = c >> 3;   // K-step 0..7
        int jt = c & 7;    // col-tile 0..7
        int j = jt * 16 + (ln & 15);
        int kb = sk * 32 + (ln >> 4) * 8;
#pragma unroll
        for (int jj = 0; jj < 8; ++jj) {
            int k = kb + jj;
            float v = (k < 128) ? load_f(Wl, isbf, (size_t)j * 128 + k)
                                : load_f(Wr, isbf, (size_t)j * 128 + (k - 128));
            Wout[tt * 8 + jj] = f2b(v);
        }
        return;
    }
    if (blk == cvb + 12) {
        int is64, isbf;
        self_detect(nullptr, (const u32*)xraw, is64, isbf);
        if (t < 642) {
            float v;
            if (t < 128) v = load_f(b1, isbf, t);
            else if (t < 256) v = load_f(b2, isbf, t - 128);
            else if (t < 384) v = load_f(b3, isbf, t - 256);
            else if (t < 640) v = load_f(Wo, isbf, t - 384);
            else v = load_f(bo, isbf, t - 640);
            smalls[t] = v;
        }
        return;
    }

    // ---- scatter role ----
    int is64, isbf;
    self_detect(ei, nullptr, is64, isbf);
    int cbase = (blk - (cvb + 13)) * CH;
    int cn = E - cbase;
    if (cn > CH) cn = CH;
    lhist[t] = 0;
    __syncthreads();
    int mysrc[4], myb[4], mydl[4];
#pragma unroll
    for (int k = 0; k < 4; ++k) {
        int i = t + k * 1024;
        myb[k] = -1;
        if (i < cn) {
            int e = cbase + i;
            int s, d;
            if (is64) {
                s = (int)((const uint2*)ei)[(size_t)e].x;
                d = (int)((const uint2*)ei)[(size_t)E + e].x;
            } else {
                s = ei[(size_t)e];
                d = ei[(size_t)E + e];
            }
            if ((unsigned)s >= (unsigned)N) s = 0;
            if ((unsigned)d >= (unsigned)N) d = 0;
            mysrc[k] = s;
            mydl[k] = d & 255;
            myb[k] = d >> 8;
            atomicAdd(&lhist[myb[k]], 1);
        }
    }
    __syncthreads();
    int lane = t & 63, wid = t >> 6;
    int v = lhist[t];
    int inc = v;
#pragma unroll
    for (int off = 1; off < 64; off <<= 1) {
        int o = __shfl_up(inc, off);
        if (lane >= off) inc += o;
    }
    if (lane == 63) wsum[wid] = inc;
    __syncthreads();
    int wpre = 0;
    for (int w = 0; w < wid; ++w) wpre += wsum[w];
    int excl = wpre + inc - v;
    loff[t] = excl;
    lcur[t] = excl;
    if (v > 0) gofs[t] = atomicAdd(&gcur[t], v);
    __syncthreads();
#pragma unroll
    for (int k = 0; k < 4; ++k) {
        if (myb[k] >= 0) {
            int pos = atomicAdd(&lcur[myb[k]], 1);
            ebuf[pos] = (u32)mysrc[k] | ((u32)mydl[k] << 24);
            ebkt[pos] = (u16)myb[k];
        }
    }
    __syncthreads();
#pragma unroll
    for (int k = 0; k < 4; ++k) {
        int i = t + k * 1024;
        if (i < cn) {
            int bb = ebkt[i];
            int local = gofs[bb] + (i - loff[bb]);
            if (local < CAPB) csrbkt[(size_t)bb * CAPB + local] = ebuf[i];
        }
    }
}

// one block per bucket: counting-sort by dst-low, compact into csr via gtot cursor
__global__ __launch_bounds__(512) void csr_build_kernel(
    const u32* __restrict__ csrbkt, const int* __restrict__ gcur,
    int N, int* __restrict__ gtot,
    int* __restrict__ offs, int* __restrict__ cnt,
    int* __restrict__ csr) {
    __shared__ int lh[256], lcur[256], wsum[4];
    __shared__ int sbase;
    __shared__ u32 sbuf[CAPB];
    int t = threadIdx.x;  // 512
    int b = blockIdx.x;
    int cb = gcur[b];
    if (cb > CAPB) cb = CAPB;
    const u32* bsrc = csrbkt + (size_t)b * CAPB;
    int d0 = b << 8;
    if (t < 256) lh[t] = 0;
    __syncthreads();
    for (int i = t; i < cb; i += 512) atomicAdd(&lh[bsrc[i] >> 24], 1);
    __syncthreads();
    int lane = t & 63, wid = t >> 6;
    if (t < 256) {
        int v = lh[t];
        int inc = v;
#pragma unroll
        for (int off = 1; off < 64; off <<= 1) {
            int o = __shfl_up(inc, off);
            if (lane >= off) inc += o;
        }
        if (lane == 63) wsum[wid] = inc;
    }
    __syncthreads();
    if (t < 256) {
        int v = lh[t];
        int inc = v;
#pragma unroll
        for (int off = 1; off < 64; off <<= 1) {
            int o = __shfl_up(inc, off);
            if (lane >= off) inc += o;
        }
        int wpre = 0;
        for (int w = 0; w < wid; ++w) wpre += wsum[w];
        int excl = wpre + inc - v;
        lcur[t] = excl;
        int d = d0 + t;
        if (d < N) {
            lh[t] = excl;  // stash excl (reuse lh)
            cnt[d] = v;
        }
    }
    if (t == 0) sbase = atomicAdd(gtot, cb);
    __syncthreads();
    int base = sbase;
    if (t < 256) {
        int d = d0 + t;
        if (d < N) offs[d] = base + lh[t];
    }
    for (int i = t; i < cb; i += 512) {
        u32 e = bsrc[i];
        int pos = atomicAdd(&lcur[e >> 24], 1);
        sbuf[pos] = e & 0xFFFFFFu;
    }
    __syncthreads();
    for (int i = t; i < cb; i += 512) csr[base + i] = (int)sbuf[i];
}

// ---------------- fused layer v5: R9 base + barrier-shadow prefetch + B dbuf ----------------
// R9 (70.4 µs) = proven gather (42.5) + ~28 µs post-barrier GEMM exposure.
// The exposure = two serial latency chains AFTER the barrier: 4 own-A HBM
// loads (~900 cy each) + 8 B L2 loads (~250 cy) inside the MFMA loop.
// v5 keeps R9's grid/gather byte-identical and:
//  (1) issues aOwn[4] + the first B pair AFTER the gather loop but BEFORE
//      __syncthreads -> latency hides under the barrier wait (waves idle
//      there anyway waiting on sibling gather tails). Register lifetime
//      spans only the barrier, not the gather (R10's spill trap avoided).
//  (2) double-buffers B inside the MFMA loop (R8-proven): exposed B chain
//      250*8 -> 250 + 8*MFMA.
__global__ __launch_bounds__(256, 4) void layer_kernel(
    const u32* __restrict__ xcur, u32* __restrict__ xnxt,
    const int* __restrict__ offs, const int* __restrict__ cnt,
    const int* __restrict__ csr,
    const u16* __restrict__ Wcp, const float* __restrict__ biasf,
    int N, int relu, const float* __restrict__ headw,
    const u32* __restrict__ xw, void* __restrict__ outp, int tstride) {
    __shared__ u32 aggL[16][68];
    __shared__ float hsum[16][2];
    int sub = blockIdx.x / tstride;
    int tile = blockIdx.x % tstride;
    int t = threadIdx.x;
    int w = t >> 6;
    int lane = t & 63;
    int nd0b = tile * 128 + sub * 16;
    if (nd0b >= N) return;
    if (t < 32) ((float*)hsum)[t] = 0.f;

    int r16 = lane & 15;
    int g4 = lane >> 4;
    int noder = nd0b + r16;
    int nodeC = (noder < N) ? noder : (N - 1);

    // ---- gather phase (byte-equivalent to proven agg; output -> LDS) ----
    int nd0 = nd0b + w * 4;
    int nd1 = nd0 + 4 < N ? nd0 + 4 : N;
    for (int nd = nd0; nd < nd1; ++nd) {
        int start = offs[nd];
        int num = cnt[nd];
        float a0 = 0.f, a1 = 0.f;
        int i = 0;
        for (; i + 8 <= num; i += 8) {
            int s0 = csr[start + i + 0], s1 = csr[start + i + 1];
            int s2 = csr[start + i + 2], s3 = csr[start + i + 3];
            int s4 = csr[start + i + 4], s5 = csr[start + i + 5];
            int s6 = csr[start + i + 6], s7 = csr[start + i + 7];
            u32 u0 = xcur[(size_t)s0 * 64 + lane];
            u32 u1 = xcur[(size_t)s1 * 64 + lane];
            u32 u2 = xcur[(size_t)s2 * 64 + lane];
            u32 u3 = xcur[(size_t)s3 * 64 + lane];
            u32 u4 = xcur[(size_t)s4 * 64 + lane];
            u32 u5 = xcur[(size_t)s5 * 64 + lane];
            u32 u6 = xcur[(size_t)s6 * 64 + lane];
            u32 u7 = xcur[(size_t)s7 * 64 + lane];
            a0 += lo2f(u0) + lo2f(u1) + lo2f(u2) + lo2f(u3) +
                  lo2f(u4) + lo2f(u5) + lo2f(u6) + lo2f(u7);
            a1 += hi2f(u0) + hi2f(u1) + hi2f(u2) + hi2f(u3) +
                  hi2f(u4) + hi2f(u5) + hi2f(u6) + hi2f(u7);
        }
        for (; i + 4 <= num; i += 4) {
            int s0 = csr[start + i + 0], s1 = csr[start + i + 1];
            int s2 = csr[start + i + 2], s3 = csr[start + i + 3];
            u32 u0 = xcur[(size_t)s0 * 64 + lane];
            u32 u1 = xcur[(size_t)s1 * 64 + lane];
            u32 u2 = xcur[(size_t)s2 * 64 + lane];
            u32 u3 = xcur[(size_t)s3 * 64 + lane];
            a0 += lo2f(u0) + lo2f(u1) + lo2f(u2) + lo2f(u3);
            a1 += hi2f(u0) + hi2f(u1) + hi2f(u2) + hi2f(u3);
        }
        for (; i < num; ++i) {
            u32 u = xcur[(size_t)csr[start + i] * 64 + lane];
            a0 += lo2f(u);
            a1 += hi2f(u);
        }
        float sc = 1.0f / (float)(num > 1 ? num : 1);
        a0 *= sc;
        a1 *= sc;
        aggL[nd - nd0b][lane] = (u32)f2b(a0) | ((u32)f2b(a1) << 16);
    }

    // ---- barrier-shadow prefetch: own-A rows (HBM) + first B pair (L2) ----
    bf16x8 aOwn[4];
#pragma unroll
    for (int s = 0; s < 4; ++s)
        aOwn[s] = *reinterpret_cast<const bf16x8*>(
            xcur + (size_t)nodeC * 64 + s * 16 + g4 * 4);
    const u16* bbase = Wcp + (size_t)lane * 8 + (size_t)(w * 2) * 512;
    bf16x8 c0 = *reinterpret_cast<const bf16x8*>(bbase);
    bf16x8 c1 = *reinterpret_cast<const bf16x8*>(bbase + 512);

    __syncthreads();

    // ---- MFMA phase: B double-buffered, A from LDS/regs ----
    floatx4 acc0 = 0.0f, acc1 = 0.0f;
#pragma unroll
    for (int s = 0; s < 8; ++s) {
        bf16x8 n0, n1;
        if (s < 7) {
            const u16* np = bbase + (size_t)((s + 1) * 8) * 512;
            n0 = *reinterpret_cast<const bf16x8*>(np);
            n1 = *reinterpret_cast<const bf16x8*>(np + 512);
        }
        bf16x8 a = (s < 4)
            ? *reinterpret_cast<const bf16x8*>(&aggL[r16][s * 16 + g4 * 4])
            : aOwn[s - 4];
        acc0 = __builtin_amdgcn_mfma_f32_16x16x32_bf16(a, c0, acc0, 0, 0, 0);
        acc1 = __builtin_amdgcn_mfma_f32_16x16x32_bf16(a, c1, acc1, 0, 0, 0);
        if (s < 7) { c0 = n0; c1 = n1; }
    }
    __syncthreads();  // A-reads done (aggL reusable); hsum-zero visible

    // C/D: col = lane&15 (+tile base), row = (lane>>4)*4 + r  [verified m89/m91]
    if (outp == nullptr) {
        u16* ldsO = (u16*)aggL;  // [16][136] u16 view
        int col0 = w * 32 + r16;
        float bf0 = biasf[col0], bf1 = biasf[col0 + 16];
#pragma unroll
        for (int r = 0; r < 4; ++r) {
            int row = g4 * 4 + r;
            float v0 = acc0[r] + bf0;
            float v1 = acc1[r] + bf1;
            if (relu) { v0 = fmaxf(v0, 0.0f); v1 = fmaxf(v1, 0.0f); }
            ldsO[row * 136 + col0] = f2b(v0);
            ldsO[row * 136 + col0 + 16] = f2b(v1);
        }
        __syncthreads();
        int row = t >> 4, seg = t & 15;
        int nodeS = nd0b + row;
        if (nodeS < N) {
            const u16* lp = ldsO + row * 136 + seg * 8;
            uint2 lo = *reinterpret_cast<const uint2*>(lp);
            uint2 hi = *reinterpret_cast<const uint2*>(lp + 4);
            u32x4 o;
            o.x = lo.x; o.y = lo.y; o.z = hi.x; o.w = hi.y;
            *reinterpret_cast<u32x4*>(&xnxt[(size_t)nodeS * 64 + seg * 4]) = o;
        }
    } else {
        // fused head: h = acc + bl3; out = (h.Wo0 + bo0, h.Wo1 + bo1)
        int is64, isbf;
        self_detect(nullptr, xw, is64, isbf);  // full wave active
        int col0 = w * 32 + r16;
        int col1 = col0 + 16;
        float bf0 = biasf[col0], bf1 = biasf[col1];
        float w00 = headw[col0], w01 = headw[col1];
        float w10 = headw[128 + col0], w11 = headw[128 + col1];
#pragma unroll
        for (int r = 0; r < 4; ++r) {
            float h0 = acc0[r] + bf0;
            float h1 = acc1[r] + bf1;
            float p0 = h0 * w00 + h1 * w01;
            float p1 = h0 * w10 + h1 * w11;
#pragma unroll
            for (int off = 8; off > 0; off >>= 1) {
                p0 += __shfl_xor(p0, off);
                p1 += __shfl_xor(p1, off);
            }
            if (r16 == 0) {
                atomicAdd(&hsum[g4 * 4 + r][0], p0);
                atomicAdd(&hsum[g4 * 4 + r][1], p1);
            }
        }
        __syncthreads();
        if (t < 16) {
            int nodeS = nd0b + t;
            if (nodeS < N) {
                float o0 = hsum[t][0] + headw[256];  // bo0
                float o1 = hsum[t][1] + headw[257];  // bo1
                if (isbf)
                    ((u32*)outp)[nodeS] = (u32)f2b(o0) | ((u32)f2b(o1) << 16);
                else
                    ((float2*)outp)[nodeS] = make_float2(o0, o1);
            }
        }
    }
}

extern "C" void kernel_launch(void* const* d_in, const int* in_sizes, int n_in,
                              void* d_out, int out_size, void* d_ws, size_t ws_size,
                              hipStream_t stream) {
    const int N = in_sizes[0] / 128;
    const int E = in_sizes[1] / 2;

    const void* x = d_in[0];
    const int* ei = (const int*)d_in[1];
    const void* Wl[3] = {d_in[2], d_in[5], d_in[8]};
    const void* bl[3] = {d_in[3], d_in[6], d_in[9]};
    const void* Wr[3] = {d_in[4], d_in[7], d_in[10]};
    const void* Wo = d_in[11];
    const void* bo = d_in[12];

    // workspace bump allocator (256B aligned)
    char* p = (char*)d_ws;
    auto alloc = [&](size_t bytes) -> char* {
        char* r = p;
        p += (bytes + 255) & ~(size_t)255;
        return r;
    };
    int* offs = (int*)alloc((size_t)N * 4);
    int* cnt = (int*)alloc((size_t)N * 4);
    float* smalls = (float*)alloc(642 * 4);
    int* gcur = (int*)alloc(1025 * 4);  // [1024] = gtot
    int* csr = (int*)alloc(((size_t)E + CAPB + 64) * 4);  // over-alloc: padded reads safe
    u16* Wcp = (u16*)alloc((size_t)3 * 4096 * 8 * 2);
    u32* x0 = (u32*)alloc((size_t)(N + 1) * 64 * 4);
    u32* x1 = (u32*)alloc((size_t)(N + 1) * 64 * 4);  // aliased as csrbkt during build
    u32* csrbkt = x1;                                  // dead until layers start
    int* gtot = gcur + 1024;
    (void)ws_size;

    const int NB = (N + 255) / 256;          // buckets
    const int cvb = (N * 16 + 1023) / 1024;  // convert blocks (1024 thr)
    const int sb = (E + CH - 1) / CH;        // scatter blocks
    const int gb = (N + 127) / 128;          // tiles (128 nodes)
    const int tstride = (gb + 7) & ~7;       // tile stride, mult of 8 (XCD affinity)
    const int ab = 8 * tstride;              // layer blocks: 8 sub-blocks x tstride tiles

    hipMemsetAsync(gcur, 0, 1025 * 4, stream);
    front_kernel<<<cvb + 13 + sb, 1024, 0, stream>>>(
        x, ei, E, N, cvb, x0, gcur, csrbkt,
        Wl[0], Wr[0], Wl[1], Wr[1], Wl[2], Wr[2],
        bl[0], bl[1], bl[2], Wo, bo, Wcp, smalls);
    csr_build_kernel<<<NB, 512, 0, stream>>>(csrbkt, gcur, N, gtot, offs, cnt, csr);

    // layer 1: x0 -> x1
    layer_kernel<<<ab, 256, 0, stream>>>(x0, x1, offs, cnt, csr, Wcp, smalls, N, 1,
                                         nullptr, nullptr, nullptr, tstride);
    // layer 2: x1 -> x0
    layer_kernel<<<ab, 256, 0, stream>>>(x1, x0, offs, cnt, csr, Wcp + 32768, smalls + 128, N, 1,
                                         nullptr, nullptr, nullptr, tstride);
    // layer 3 + fused head: x0 -> d_out
    layer_kernel<<<ab, 256, 0, stream>>>(x0, x1, offs, cnt, csr, Wcp + 65536, smalls + 256, N, 0,
                                         smalls + 384, (const u32*)x, d_out, tstride);
}